// Round 19
// baseline (54.390 us; speedup 1.0000x reference)
//
#include <hip/hip_runtime.h>
#include <hip/hip_bf16.h>
#include <math.h>

// B=8, T=2048, C=1024, H=64.
// out = softmax( (X Wq^T)(X Wk^T)^T * C^-0.5, key mask ) @ (X Wv^T)
//
// Round 19 = R18 + LDS-only barriers (T4 / HK technique):
//  __syncthreads() compiles to "s_waitcnt vmcnt(0) lgkmcnt(0); s_barrier",
//  draining our deliberately-outstanding prefetch loads at EVERY chunk/
//  superstep boundary (the §5 barrier-drain stall). Replaced with
//  lgkmcnt(0)-only + raw s_barrier in both hot loops: LDS publication stays
//  correct; register-destined global loads stay in flight across barriers
//  (their consumers get compiler data-dep vmcnt waits = counted-vmcnt).

#define T_SEQ 2048
#define EMB 1024
#define HS 64
#define NB 8

typedef __attribute__((ext_vector_type(8))) short short8;
typedef __attribute__((ext_vector_type(4))) float f32x4;
typedef __attribute__((ext_vector_type(2))) unsigned int uint2_t;
typedef unsigned short ushort_t;

static __device__ inline ushort_t f2bf(float f) {
  union { float f; unsigned u; } v; v.f = f;
  unsigned r = v.u + 0x7FFF + ((v.u >> 16) & 1);  // RNE
  return (ushort_t)(r >> 16);
}
static __device__ inline unsigned pk2(float a, float b) {
  return (unsigned)f2bf(a) | ((unsigned)f2bf(b) << 16);
}
// LDS-publication barrier: waits own LDS ops, rendezvous; VMEM stays in flight.
static __device__ inline void lds_barrier() {
  asm volatile("s_waitcnt lgkmcnt(0)" ::: "memory");
  __builtin_amdgcn_s_barrier();
}

// ---------------- k1: W conversion (48 blocks x 256 thr) ----------------
__global__ __launch_bounds__(256) void convw_kernel(
    const float* __restrict__ Wq, const float* __restrict__ Wk,
    const float* __restrict__ Wv, ushort_t* __restrict__ Wb) {
  const int m = blockIdx.x >> 4;
  const int blk = blockIdx.x & 15;
  const float* src = (m == 0) ? Wq : (m == 1) ? Wk : Wv;
  const float scale = (m == 0) ? 0.03125f : 1.0f;  // fold C^-0.5 into Wq
  const int base = blk * 4096 + threadIdx.x * 16;
  ushort_t* dst = Wb + m * 65536;
  ushort_t tmp[16];
#pragma unroll
  for (int j = 0; j < 4; ++j) {
    float4 x = *(const float4*)(src + base + j * 4);
    tmp[j * 4 + 0] = f2bf(x.x * scale);
    tmp[j * 4 + 1] = f2bf(x.y * scale);
    tmp[j * 4 + 2] = f2bf(x.z * scale);
    tmp[j * 4 + 3] = f2bf(x.w * scale);
  }
  *(short8*)(dst + base) = *(short8*)tmp;
  *(short8*)(dst + base + 8) = *(short8*)(tmp + 8);
}

// ---------------- k2: projections (256 blocks x 256 thr) ----------------
// R15 structure; loop barriers are now LDS-only so X/W prefetches pipeline
// across chunks.
__global__ __launch_bounds__(256) void proj_kernel(
    const float* __restrict__ X, const ushort_t* __restrict__ Wb,
    ushort_t* __restrict__ Qb, ushort_t* __restrict__ Kb,
    ushort_t* __restrict__ Vtb) {
  __shared__ __align__(16) ushort_t Xs[2][64 * 128];  // 2 x 16KB bf16
  const int tid = threadIdx.x;
  const int lane = tid & 63, w = tid >> 6;
  const int l15 = lane & 15, hi = lane >> 4;
  const long rbase = (long)blockIdx.x * 64;

  const ushort_t* Wrow[3];
#pragma unroll
  for (int t = 0; t < 3; ++t) {
    const int ht = 3 * w + t, m = ht >> 2, hs = ht & 3;
    Wrow[t] = Wb + m * 65536 + (hs * 16 + l15) * 1024 + hi * 8;
  }

  short8 wfA[6], wfB[6], wfC[6], wfD[6];  // named 4-deep rotation (rule #20)
  auto loadw = [&](short8 (&dst)[6], int s) {
#pragma unroll
    for (int t = 0; t < 3; ++t) {
      dst[2 * t + 0] = *(const short8*)(Wrow[t] + s * 64);
      dst[2 * t + 1] = *(const short8*)(Wrow[t] + s * 64 + 32);
    }
  };
  loadw(wfA, 0); loadw(wfB, 1); loadw(wfC, 2);

  float4 xrA[8], xrB[8];
  auto stage_load = [&](float4 (&xr)[8], int c) {
#pragma unroll
    for (int j = 0; j < 8; ++j) {
      const int F = j * 256 + tid;
      const int row = F >> 5, c4 = F & 31;
      xr[j] = *(const float4*)(X + (rbase + row) * EMB + c * 128 + c4 * 4);
    }
  };
  auto stage_write = [&](float4 (&xr)[8], int buf) {
    ushort_t* Xd = Xs[buf];
#pragma unroll
    for (int j = 0; j < 8; ++j) {
      const int F = j * 256 + tid;
      const int row = F >> 5, c4 = F & 31;
      uint2_t pv;
      pv.x = pk2(xr[j].x, xr[j].y);
      pv.y = pk2(xr[j].z, xr[j].w);
      *(uint2_t*)((char*)(Xd + row * 128) + ((c4 * 8) ^ ((row & 7) << 4))) = pv;
    }
  };

  f32x4 acc[4][3];
#pragma unroll
  for (int rt = 0; rt < 4; ++rt)
#pragma unroll
    for (int t = 0; t < 3; ++t) acc[rt][t] = (f32x4){0.f, 0.f, 0.f, 0.f};

  const int swA = (l15 & 7) << 4;

  auto body = [&](int s, int buf, short8 (&cur)[6], short8 (&pre)[6]) {
    if (s + 3 < 16) loadw(pre, s + 3);
    const int sb = (s & 1) * 128;
#pragma unroll
    for (int rt = 0; rt < 4; ++rt) {
      const char* rowp = (const char*)(Xs[buf] + (rt * 16 + l15) * 128);
      short8 a0 = *(const short8*)(rowp + ((sb + hi * 16) ^ swA));
      short8 a1 = *(const short8*)(rowp + ((sb + 64 + hi * 16) ^ swA));
#pragma unroll
      for (int t = 0; t < 3; ++t) {
        acc[rt][t] = __builtin_amdgcn_mfma_f32_16x16x32_bf16(
            a0, cur[2 * t + 0], acc[rt][t], 0, 0, 0);
        acc[rt][t] = __builtin_amdgcn_mfma_f32_16x16x32_bf16(
            a1, cur[2 * t + 1], acc[rt][t], 0, 0, 0);
      }
    }
  };

  stage_load(xrA, 0);
  stage_write(xrA, 0);
  stage_load(xrB, 1);
  lds_barrier();

  stage_load(xrA, 2);                                   // c=0
  body(0, 0, wfA, wfD); body(1, 0, wfB, wfA);
  stage_write(xrB, 1); lds_barrier();
  stage_load(xrB, 3);                                   // c=1
  body(2, 1, wfC, wfB); body(3, 1, wfD, wfC);
  stage_write(xrA, 0); lds_barrier();
  stage_load(xrA, 4);                                   // c=2
  body(4, 0, wfA, wfD); body(5, 0, wfB, wfA);
  stage_write(xrB, 1); lds_barrier();
  stage_load(xrB, 5);                                   // c=3
  body(6, 1, wfC, wfB); body(7, 1, wfD, wfC);
  stage_write(xrA, 0); lds_barrier();
  stage_load(xrA, 6);                                   // c=4
  body(8, 0, wfA, wfD); body(9, 0, wfB, wfA);
  stage_write(xrB, 1); lds_barrier();
  stage_load(xrB, 7);                                   // c=5
  body(10, 1, wfC, wfB); body(11, 1, wfD, wfC);
  stage_write(xrA, 0); lds_barrier();
  body(12, 0, wfA, wfD); body(13, 0, wfB, wfA);         // c=6
  stage_write(xrB, 1); lds_barrier();
  body(14, 1, wfC, wfB); body(15, 1, wfD, wfC);         // c=7

  const long bblk = rbase >> 11;
  const long tb0 = rbase & 2047;
  ushort_t* outs[2] = {Qb, Kb};
#pragma unroll
  for (int rt = 0; rt < 4; ++rt)
#pragma unroll
    for (int t = 0; t < 3; ++t) {
      const int ht = 3 * w + t, m = ht >> 2, hs = ht & 3;
      const int h = hs * 16 + l15;
      if (m < 2) {
#pragma unroll
        for (int r = 0; r < 4; ++r) {
          const long row = rbase + rt * 16 + 4 * hi + r;
          outs[m][row * 64 + h] = f2bf(acc[rt][t][r]);
        }
      } else {
        const long tloc = tb0 + rt * 16 + 4 * hi;
        uint2_t v;
        v.x = pk2(acc[rt][t][0], acc[rt][t][1]);
        v.y = pk2(acc[rt][t][2], acc[rt][t][3]);
        *(uint2_t*)(Vtb + bblk * (long)HS * T_SEQ + (long)h * T_SEQ + tloc) = v;
      }
    }
}

// ---------------- k3: attention (256 blocks x 512 thr) ----------------
// R18 structure (2-tile supersteps, 4-deep buffers); loop barriers LDS-only.
__global__ __launch_bounds__(512) void attn_kernel(
    const ushort_t* __restrict__ Qb, const ushort_t* __restrict__ Kb,
    const ushort_t* __restrict__ Vtb, const int* __restrict__ mask,
    float* __restrict__ out) {
  __shared__ __align__(16) char Lds[152064];
  // Kst 0 + (g*4+buf)*8192 (64K) | Vst 65536 + (g*4+buf)*8192 (64K)
  // Ps 131072 + w*2048 (16K) | bias 147456 (4K) | alpha 151552 (512B)

  const int tid = threadIdx.x;
  const int lane = tid & 63, w = tid >> 6;
  const int l15 = lane & 15, hi = lane >> 4;
  const int qs = w & 3, g = w >> 2;   // g == tid>>8: stagers == consumers
  const int si = tid & 255;           // staging index within group
  const int id = blockIdx.x;
  const int b = id & 7;               // batch -> XCD (L2 locality)
  const int q0 = (id >> 3) * 64;

  ushort_t* biasB = (ushort_t*)(Lds + 147456);
  float* alphaArr = (float*)(Lds + 151552);

  // stage mask bias once as bf16 (512 thr x 4 keys)
  {
    const ushort_t nb = f2bf(-1e30f);
    const int* mp = mask + b * T_SEQ + tid * 4;
    int4 m0 = *(const int4*)(mp);
    ushort_t t4[4];
    t4[0] = m0.x ? nb : 0; t4[1] = m0.y ? nb : 0;
    t4[2] = m0.z ? nb : 0; t4[3] = m0.w ? nb : 0;
    *(uint2_t*)(biasB + tid * 4) = *(uint2_t*)t4;
  }

  // Q fragments (16 queries per wave)
  const ushort_t* Qrow = Qb + (long)(b * T_SEQ + q0 + qs * 16 + l15) * 64;
  const short8 qf0 = *(const short8*)(Qrow + hi * 8);
  const short8 qf1 = *(const short8*)(Qrow + 32 + hi * 8);

  const ushort_t* Kg = Kb + (long)b * T_SEQ * 64;
  const ushort_t* Vg = Vtb + (long)b * HS * T_SEQ;

  // ---- staging (group g's 256 threads; 2 short8 each for K and V)
  short8 kregA[2], vregA[2], kregB[2], vregB[2];  // named 2-tile sets
  auto stage_load = [&](short8 (&kreg)[2], short8 (&vreg)[2], int t) {
    const ushort_t* ktile = Kg + (g * 1024 + t * 64) * 64;  // 8KB contiguous
#pragma unroll
    for (int j = 0; j < 2; ++j)
      kreg[j] = *(const short8*)(ktile + (j * 32 + (si >> 3)) * 64 + (si & 7) * 8);
    const ushort_t* vtile = Vg + (long)(si >> 2) * T_SEQ + g * 1024 + t * 64;
#pragma unroll
    for (int j = 0; j < 2; ++j)
      vreg[j] = *(const short8*)(vtile + (si & 3) * 8 + j * 32);
  };
  auto stage_write = [&](short8 (&kreg)[2], short8 (&vreg)[2], int buf) {
    char* Kd = Lds + (g * 4 + buf) * 8192;
#pragma unroll
    for (int j = 0; j < 2; ++j) {
      const int row = j * 32 + (si >> 3);
      *(short8*)(Kd + row * 128 + (((si & 7) * 16) ^ ((row & 7) << 4))) = kreg[j];
    }
    char* Vd = Lds + 65536 + (g * 4 + buf) * 8192;
    const int vrow = si >> 2, sv = (vrow & 7) << 4;
#pragma unroll
    for (int j = 0; j < 2; ++j)
      *(short8*)(Vd + vrow * 128 + ((((si & 3) * 16) + j * 64) ^ sv)) = vreg[j];
  };

  f32x4 O[4];
#pragma unroll
  for (int ht = 0; ht < 4; ++ht) O[ht] = (f32x4){0.f, 0.f, 0.f, 0.f};
  float mrow = -1e30f, lsum = 0.f;

  char* prow = Lds + 131072 + w * 2048 + l15 * 128;
  const int sw = (l15 & 7) << 4;
  const int swr = (l15 & 7) << 4;  // row-swizzle for K/V frag reads

  // ---- one tile's compute (identical math to R10-R18)
  auto tile_compute = [&](int t, int buf) {
    f32x4 s[4];
    const char* Kl = Lds + (g * 4 + buf) * 8192;
    __builtin_amdgcn_s_setprio(1);
#pragma unroll
    for (int kt = 0; kt < 4; ++kt) {
      const char* kr = Kl + (kt * 16 + l15) * 128;
      short8 k0 = *(const short8*)(kr + ((hi * 16) ^ swr));
      short8 k1 = *(const short8*)(kr + ((64 + hi * 16) ^ swr));
      f32x4 z = {0.f, 0.f, 0.f, 0.f};
      s[kt] = __builtin_amdgcn_mfma_f32_16x16x32_bf16(k0, qf0, z, 0, 0, 0);
      s[kt] = __builtin_amdgcn_mfma_f32_16x16x32_bf16(k1, qf1, s[kt], 0, 0, 0);
    }
    __builtin_amdgcn_s_setprio(0);

    const ushort_t* blp = biasB + g * 1024 + t * 64;
#pragma unroll
    for (int kt = 0; kt < 4; ++kt) {
      const uint2_t bu = *(const uint2_t*)(blp + kt * 16 + hi * 4);
      union { unsigned u; float f; } c0, c1, c2, c3;
      c0.u = bu.x << 16; c1.u = bu.x & 0xFFFF0000u;
      c2.u = bu.y << 16; c3.u = bu.y & 0xFFFF0000u;
      s[kt][0] += c0.f; s[kt][1] += c1.f;
      s[kt][2] += c2.f; s[kt][3] += c3.f;
    }

    float t0m = fmaxf(fmaxf(s[0][0], s[0][1]), fmaxf(s[0][2], s[0][3]));
    float t1m = fmaxf(fmaxf(s[1][0], s[1][1]), fmaxf(s[1][2], s[1][3]));
    float t2m = fmaxf(fmaxf(s[2][0], s[2][1]), fmaxf(s[2][2], s[2][3]));
    float t3m = fmaxf(fmaxf(s[3][0], s[3][1]), fmaxf(s[3][2], s[3][3]));
    float mt = fmaxf(fmaxf(t0m, t1m), fmaxf(t2m, t3m));
    mt = fmaxf(mt, __shfl_xor(mt, 16, 64));
    mt = fmaxf(mt, __shfl_xor(mt, 32, 64));

    const bool skip = __all(mt <= mrow + 8.0f);
    float mnew = mrow;
    if (!skip) {
      mnew = fmaxf(mrow, mt);
      const float alpha = __expf(mrow - mnew);
      if (lane < 16) alphaArr[w * 16 + l15] = alpha;
      lsum *= alpha;
      mrow = mnew;
    }

    float psum = 0.f;
#pragma unroll
    for (int kt = 0; kt < 4; ++kt) {
      const float p0 = __expf(s[kt][0] - mnew);
      const float p1 = __expf(s[kt][1] - mnew);
      const float p2 = __expf(s[kt][2] - mnew);
      const float p3 = __expf(s[kt][3] - mnew);
      psum += (p0 + p1) + (p2 + p3);
      const int a0 = (kt * 32 + hi * 8) ^ sw;
      *(unsigned*)(prow + a0) = pk2(p0, p1);
      *(unsigned*)(prow + a0 + 4) = pk2(p2, p3);
    }
    lsum += psum;

    if (!skip) {
      const f32x4 av = *(const f32x4*)(alphaArr + w * 16 + 4 * hi);
#pragma unroll
      for (int ht = 0; ht < 4; ++ht) O[ht] *= av;
    }

    short8 pa0 = *(const short8*)(prow + ((hi * 16) ^ sw));
    short8 pa1 = *(const short8*)(prow + ((64 + hi * 16) ^ sw));
    const char* Vl = Lds + 65536 + (g * 4 + buf) * 8192;
    __builtin_amdgcn_s_setprio(1);
#pragma unroll
    for (int ht = 0; ht < 4; ++ht) {
      const char* vr = Vl + (ht * 16 + l15) * 128;
      short8 v0 = *(const short8*)(vr + ((hi * 16) ^ swr));
      short8 v1 = *(const short8*)(vr + ((64 + hi * 16) ^ swr));
      O[ht] = __builtin_amdgcn_mfma_f32_16x16x32_bf16(pa0, v0, O[ht], 0, 0, 0);
      O[ht] = __builtin_amdgcn_mfma_f32_16x16x32_bf16(pa1, v1, O[ht], 0, 0, 0);
    }
    __builtin_amdgcn_s_setprio(0);
  };

  // prologue: tiles 0,1 staged (barrier also publishes bias)
  stage_load(kregA, vregA, 0);
  stage_load(kregB, vregB, 1);
  stage_write(kregA, vregA, 0);
  stage_write(kregB, vregB, 1);
  lds_barrier();

#pragma unroll 1
  for (int ts = 0; ts < 16; ts += 2) {
    // T14: issue next superstep's loads; 2 tiles of compute cover them
    if (ts + 2 < 16) {
      stage_load(kregA, vregA, ts + 2);
      stage_load(kregB, vregB, ts + 3);
    }
    tile_compute(ts, ts & 3);
    tile_compute(ts + 1, (ts + 1) & 3);
    if (ts + 2 < 16) {
      stage_write(kregA, vregA, (ts + 2) & 3);
      stage_write(kregB, vregB, (ts + 3) & 3);
    }
    lds_barrier();  // LDS-only: prefetch loads stay in flight
  }

  // per-query l (reduce over hi groups)
  lsum += __shfl_xor(lsum, 16, 64);
  lsum += __shfl_xor(lsum, 32, 64);

  // split-2 merge: group 1 publishes, group 0 combines + stores.
  float* mergeF = (float*)Lds;
  if (g == 1) {
    float* ml = mergeF + (qs * 64 + lane) * 18;
    ml[0] = mrow; ml[1] = lsum;
#pragma unroll
    for (int ht = 0; ht < 4; ++ht)
#pragma unroll
      for (int r = 0; r < 4; ++r) ml[2 + ht * 4 + r] = O[ht][r];
  }
  lds_barrier();
  if (g == 0) {
    const float* ml = mergeF + (qs * 64 + lane) * 18;
    const float mB = ml[0], lB = ml[1];
    const float mn = fmaxf(mrow, mB);
    const float aa = __expf(mrow - mn);
    const float ab = __expf(mB - mn);
    const float inv = 1.0f / (lsum * aa + lB * ab);
    float* ob = out + (long)(b * T_SEQ + q0 + qs * 16) * 64;
#pragma unroll
    for (int r = 0; r < 4; ++r) {
      const float aar = __shfl(aa, 4 * hi + r, 64);
      const float abr = __shfl(ab, 4 * hi + r, 64);
      const float invr = __shfl(inv, 4 * hi + r, 64);
#pragma unroll
      for (int ht = 0; ht < 4; ++ht)
        ob[(4 * hi + r) * 64 + ht * 16 + l15] =
            (O[ht][r] * aar + ml[2 + ht * 4 + r] * abr) * invr;
    }
  }
}

// ---------------- launch ----------------
extern "C" void kernel_launch(void* const* d_in, const int* in_sizes, int n_in,
                              void* d_out, int out_size, void* d_ws, size_t ws_size,
                              hipStream_t stream) {
  const float* X  = (const float*)d_in[0];
  const float* Wq = (const float*)d_in[1];
  const float* Wk = (const float*)d_in[2];
  const float* Wv = (const float*)d_in[3];
  const int* mask = (const int*)d_in[4];
  float* outp = (float*)d_out;

  const long NT = (long)NB * T_SEQ * HS;
  ushort_t* wsb = (ushort_t*)d_ws;
  ushort_t* Qb  = wsb;            // 2 MB
  ushort_t* Kb  = wsb + NT;       // 2 MB
  ushort_t* Vtb = wsb + 2 * NT;   // 2 MB (per-batch transposed V)
  ushort_t* Wb  = wsb + 3 * NT;   // 384 KB

  convw_kernel<<<48, 256, 0, stream>>>(Wq, Wk, Wv, Wb);
  proj_kernel<<<(NB * T_SEQ) / 64, 256, 0, stream>>>(X, Wb, Qb, Kb, Vtb);
  attn_kernel<<<256, 512, 0, stream>>>(Qb, Kb, Vtb, mask, outp);
}

// Round 20
// 53.794 us; speedup vs baseline: 1.0111x; 1.0111x over previous
//
#include <hip/hip_runtime.h>
#include <hip/hip_bf16.h>
#include <math.h>

// B=8, T=2048, C=1024, H=64.
// out = softmax( (X Wq^T)(X Wk^T)^T * C^-0.5, key mask ) @ (X Wv^T)
//
// Round 20 = R18/R19 + two attn overhead removals:
//  * K/V staging via global_load_lds width=16 (pre-swizzled global source,
//    linear LDS dest -- the R12-verified pattern). No ds_writes, no kreg/vreg.
//    Superstep barrier = __syncthreads (vmcnt drain required for lds-destined
//    loads; R19 proved the drain is free here).
//  * exp2-domain softmax: log2e folded into Wq (convw), __expf -> exp2f
//    (raw v_exp_f32), defer threshold 8 -> 11.5416. Identical math.
//  * proj: R19-exact (lds_barrier version, passed).

#define T_SEQ 2048
#define EMB 1024
#define HS 64
#define NB 8

typedef __attribute__((ext_vector_type(8))) short short8;
typedef __attribute__((ext_vector_type(4))) float f32x4;
typedef __attribute__((ext_vector_type(2))) unsigned int uint2_t;
typedef unsigned short ushort_t;

static __device__ inline ushort_t f2bf(float f) {
  union { float f; unsigned u; } v; v.f = f;
  unsigned r = v.u + 0x7FFF + ((v.u >> 16) & 1);  // RNE
  return (ushort_t)(r >> 16);
}
static __device__ inline unsigned pk2(float a, float b) {
  return (unsigned)f2bf(a) | ((unsigned)f2bf(b) << 16);
}
static __device__ inline void lds_barrier() {
  asm volatile("s_waitcnt lgkmcnt(0)" ::: "memory");
  __builtin_amdgcn_s_barrier();
}

#define GL16(gp, lp)                                                 \
  __builtin_amdgcn_global_load_lds(                                  \
      (const __attribute__((address_space(1))) void*)(gp),           \
      (__attribute__((address_space(3))) void*)(lp), 16, 0, 0)

// ---------------- k1: W conversion (48 blocks x 256 thr) ----------------
__global__ __launch_bounds__(256) void convw_kernel(
    const float* __restrict__ Wq, const float* __restrict__ Wk,
    const float* __restrict__ Wv, ushort_t* __restrict__ Wb) {
  const int m = blockIdx.x >> 4;
  const int blk = blockIdx.x & 15;
  const float* src = (m == 0) ? Wq : (m == 1) ? Wk : Wv;
  // Wq: fold C^-0.5 AND log2(e) (exp2-domain softmax downstream)
  const float scale = (m == 0) ? 0.03125f * 1.44269504f : 1.0f;
  const int base = blk * 4096 + threadIdx.x * 16;
  ushort_t* dst = Wb + m * 65536;
  ushort_t tmp[16];
#pragma unroll
  for (int j = 0; j < 4; ++j) {
    float4 x = *(const float4*)(src + base + j * 4);
    tmp[j * 4 + 0] = f2bf(x.x * scale);
    tmp[j * 4 + 1] = f2bf(x.y * scale);
    tmp[j * 4 + 2] = f2bf(x.z * scale);
    tmp[j * 4 + 3] = f2bf(x.w * scale);
  }
  *(short8*)(dst + base) = *(short8*)tmp;
  *(short8*)(dst + base + 8) = *(short8*)(tmp + 8);
}

// ---------------- k2: projections (256 blocks x 256 thr) ---------------- (R19)
__global__ __launch_bounds__(256) void proj_kernel(
    const float* __restrict__ X, const ushort_t* __restrict__ Wb,
    ushort_t* __restrict__ Qb, ushort_t* __restrict__ Kb,
    ushort_t* __restrict__ Vtb) {
  __shared__ __align__(16) ushort_t Xs[2][64 * 128];  // 2 x 16KB bf16
  const int tid = threadIdx.x;
  const int lane = tid & 63, w = tid >> 6;
  const int l15 = lane & 15, hi = lane >> 4;
  const long rbase = (long)blockIdx.x * 64;

  const ushort_t* Wrow[3];
#pragma unroll
  for (int t = 0; t < 3; ++t) {
    const int ht = 3 * w + t, m = ht >> 2, hs = ht & 3;
    Wrow[t] = Wb + m * 65536 + (hs * 16 + l15) * 1024 + hi * 8;
  }

  short8 wfA[6], wfB[6], wfC[6], wfD[6];  // named 4-deep rotation (rule #20)
  auto loadw = [&](short8 (&dst)[6], int s) {
#pragma unroll
    for (int t = 0; t < 3; ++t) {
      dst[2 * t + 0] = *(const short8*)(Wrow[t] + s * 64);
      dst[2 * t + 1] = *(const short8*)(Wrow[t] + s * 64 + 32);
    }
  };
  loadw(wfA, 0); loadw(wfB, 1); loadw(wfC, 2);

  float4 xrA[8], xrB[8];
  auto stage_load = [&](float4 (&xr)[8], int c) {
#pragma unroll
    for (int j = 0; j < 8; ++j) {
      const int F = j * 256 + tid;
      const int row = F >> 5, c4 = F & 31;
      xr[j] = *(const float4*)(X + (rbase + row) * EMB + c * 128 + c4 * 4);
    }
  };
  auto stage_write = [&](float4 (&xr)[8], int buf) {
    ushort_t* Xd = Xs[buf];
#pragma unroll
    for (int j = 0; j < 8; ++j) {
      const int F = j * 256 + tid;
      const int row = F >> 5, c4 = F & 31;
      uint2_t pv;
      pv.x = pk2(xr[j].x, xr[j].y);
      pv.y = pk2(xr[j].z, xr[j].w);
      *(uint2_t*)((char*)(Xd + row * 128) + ((c4 * 8) ^ ((row & 7) << 4))) = pv;
    }
  };

  f32x4 acc[4][3];
#pragma unroll
  for (int rt = 0; rt < 4; ++rt)
#pragma unroll
    for (int t = 0; t < 3; ++t) acc[rt][t] = (f32x4){0.f, 0.f, 0.f, 0.f};

  const int swA = (l15 & 7) << 4;

  auto body = [&](int s, int buf, short8 (&cur)[6], short8 (&pre)[6]) {
    if (s + 3 < 16) loadw(pre, s + 3);
    const int sb = (s & 1) * 128;
#pragma unroll
    for (int rt = 0; rt < 4; ++rt) {
      const char* rowp = (const char*)(Xs[buf] + (rt * 16 + l15) * 128);
      short8 a0 = *(const short8*)(rowp + ((sb + hi * 16) ^ swA));
      short8 a1 = *(const short8*)(rowp + ((sb + 64 + hi * 16) ^ swA));
#pragma unroll
      for (int t = 0; t < 3; ++t) {
        acc[rt][t] = __builtin_amdgcn_mfma_f32_16x16x32_bf16(
            a0, cur[2 * t + 0], acc[rt][t], 0, 0, 0);
        acc[rt][t] = __builtin_amdgcn_mfma_f32_16x16x32_bf16(
            a1, cur[2 * t + 1], acc[rt][t], 0, 0, 0);
      }
    }
  };

  stage_load(xrA, 0);
  stage_write(xrA, 0);
  stage_load(xrB, 1);
  lds_barrier();

  stage_load(xrA, 2);                                   // c=0
  body(0, 0, wfA, wfD); body(1, 0, wfB, wfA);
  stage_write(xrB, 1); lds_barrier();
  stage_load(xrB, 3);                                   // c=1
  body(2, 1, wfC, wfB); body(3, 1, wfD, wfC);
  stage_write(xrA, 0); lds_barrier();
  stage_load(xrA, 4);                                   // c=2
  body(4, 0, wfA, wfD); body(5, 0, wfB, wfA);
  stage_write(xrB, 1); lds_barrier();
  stage_load(xrB, 5);                                   // c=3
  body(6, 1, wfC, wfB); body(7, 1, wfD, wfC);
  stage_write(xrA, 0); lds_barrier();
  stage_load(xrA, 6);                                   // c=4
  body(8, 0, wfA, wfD); body(9, 0, wfB, wfA);
  stage_write(xrB, 1); lds_barrier();
  stage_load(xrB, 7);                                   // c=5
  body(10, 1, wfC, wfB); body(11, 1, wfD, wfC);
  stage_write(xrA, 0); lds_barrier();
  body(12, 0, wfA, wfD); body(13, 0, wfB, wfA);         // c=6
  stage_write(xrB, 1); lds_barrier();
  body(14, 1, wfC, wfB); body(15, 1, wfD, wfC);         // c=7

  const long bblk = rbase >> 11;
  const long tb0 = rbase & 2047;
  ushort_t* outs[2] = {Qb, Kb};
#pragma unroll
  for (int rt = 0; rt < 4; ++rt)
#pragma unroll
    for (int t = 0; t < 3; ++t) {
      const int ht = 3 * w + t, m = ht >> 2, hs = ht & 3;
      const int h = hs * 16 + l15;
      if (m < 2) {
#pragma unroll
        for (int r = 0; r < 4; ++r) {
          const long row = rbase + rt * 16 + 4 * hi + r;
          outs[m][row * 64 + h] = f2bf(acc[rt][t][r]);
        }
      } else {
        const long tloc = tb0 + rt * 16 + 4 * hi;
        uint2_t v;
        v.x = pk2(acc[rt][t][0], acc[rt][t][1]);
        v.y = pk2(acc[rt][t][2], acc[rt][t][3]);
        *(uint2_t*)(Vtb + bblk * (long)HS * T_SEQ + (long)h * T_SEQ + tloc) = v;
      }
    }
}

// ---------------- k3: attention (256 blocks x 512 thr) ----------------
// R18 geometry (64q, 8 waves = 4 qs x 2 g, 4-deep buffers, 2-tile supersteps)
// with global_load_lds staging (pre-swizzled source, linear LDS dest) and
// exp2-domain softmax. LDS pool (152064B):
//   Kst 0 + (g*4+buf)*8192 | Vst 65536 + (g*4+buf)*8192
//   Ps 131072 + w*2048 | bias 147456 | alpha 151552
__global__ __launch_bounds__(512) void attn_kernel(
    const ushort_t* __restrict__ Qb, const ushort_t* __restrict__ Kb,
    const ushort_t* __restrict__ Vtb, const int* __restrict__ mask,
    float* __restrict__ out) {
  __shared__ __align__(16) char Lds[152064];

  const int tid = threadIdx.x;
  const int lane = tid & 63, w = tid >> 6;
  const int l15 = lane & 15, hi = lane >> 4;
  const int qs = w & 3, g = w >> 2;   // g == tid>>8: stagers == consumers
  const int si = tid & 255;           // staging index within group
  const int id = blockIdx.x;
  const int b = id & 7;               // batch -> XCD (L2 locality)
  const int q0 = (id >> 3) * 64;

  ushort_t* biasB = (ushort_t*)(Lds + 147456);
  float* alphaArr = (float*)(Lds + 151552);

  // stage mask bias once as bf16 (512 thr x 4 keys)
  {
    const ushort_t nb = f2bf(-1e30f);
    const int* mp = mask + b * T_SEQ + tid * 4;
    int4 m0 = *(const int4*)(mp);
    ushort_t t4[4];
    t4[0] = m0.x ? nb : 0; t4[1] = m0.y ? nb : 0;
    t4[2] = m0.z ? nb : 0; t4[3] = m0.w ? nb : 0;
    *(uint2_t*)(biasB + tid * 4) = *(uint2_t*)t4;
  }

  // Q fragments (16 queries per wave)
  const ushort_t* Qrow = Qb + (long)(b * T_SEQ + q0 + qs * 16 + l15) * 64;
  const short8 qf0 = *(const short8*)(Qrow + hi * 8);
  const short8 qf1 = *(const short8*)(Qrow + 32 + hi * 8);

  const ushort_t* Kg = Kb + (long)b * T_SEQ * 64;
  const ushort_t* Vg = Vtb + (long)b * HS * T_SEQ;

  // ---- staging via global_load_lds: flat slot F=j*256+si, row=F>>3,
  // slot=F&7; global source pre-swizzled slot^=(row&7) so the LINEAR LDS
  // write produces the layout the (verified) swizzled reads expect.
  auto stage_gl = [&](int t, int buf) {
    char* Kd = Lds + (g * 4 + buf) * 8192;
    const ushort_t* ktile = Kg + (g * 1024 + t * 64) * 64;
#pragma unroll
    for (int j = 0; j < 2; ++j) {
      const int F = j * 256 + si;
      const int row = F >> 3, sl = F & 7;
      const int gsl = sl ^ (row & 7);
      GL16(ktile + row * 64 + gsl * 8, Kd + F * 16);
    }
    char* Vd = Lds + 65536 + (g * 4 + buf) * 8192;
    const ushort_t* vtile = Vg + g * 1024 + t * 64;
#pragma unroll
    for (int j = 0; j < 2; ++j) {
      const int F = j * 256 + si;
      const int row = F >> 3, sl = F & 7;
      const int gsl = sl ^ (row & 7);
      GL16(vtile + (long)row * T_SEQ + gsl * 8, Vd + F * 16);
    }
  };

  f32x4 O[4];
#pragma unroll
  for (int ht = 0; ht < 4; ++ht) O[ht] = (f32x4){0.f, 0.f, 0.f, 0.f};
  float mrow = -1e30f, lsum = 0.f;

  char* prow = Lds + 131072 + w * 2048 + l15 * 128;
  const int sw = (l15 & 7) << 4;
  const int swr = (l15 & 7) << 4;  // row-swizzle for K/V frag reads

  // ---- one tile's compute (R18 math, exp2 domain)
  auto tile_compute = [&](int t, int buf) {
    f32x4 s[4];
    const char* Kl = Lds + (g * 4 + buf) * 8192;
    __builtin_amdgcn_s_setprio(1);
#pragma unroll
    for (int kt = 0; kt < 4; ++kt) {
      const char* kr = Kl + (kt * 16 + l15) * 128;
      short8 k0 = *(const short8*)(kr + ((hi * 16) ^ swr));
      short8 k1 = *(const short8*)(kr + ((64 + hi * 16) ^ swr));
      f32x4 z = {0.f, 0.f, 0.f, 0.f};
      s[kt] = __builtin_amdgcn_mfma_f32_16x16x32_bf16(k0, qf0, z, 0, 0, 0);
      s[kt] = __builtin_amdgcn_mfma_f32_16x16x32_bf16(k1, qf1, s[kt], 0, 0, 0);
    }
    __builtin_amdgcn_s_setprio(0);

    const ushort_t* blp = biasB + g * 1024 + t * 64;
#pragma unroll
    for (int kt = 0; kt < 4; ++kt) {
      const uint2_t bu = *(const uint2_t*)(blp + kt * 16 + hi * 4);
      union { unsigned u; float f; } c0, c1, c2, c3;
      c0.u = bu.x << 16; c1.u = bu.x & 0xFFFF0000u;
      c2.u = bu.y << 16; c3.u = bu.y & 0xFFFF0000u;
      s[kt][0] += c0.f; s[kt][1] += c1.f;
      s[kt][2] += c2.f; s[kt][3] += c3.f;
    }

    float t0m = fmaxf(fmaxf(s[0][0], s[0][1]), fmaxf(s[0][2], s[0][3]));
    float t1m = fmaxf(fmaxf(s[1][0], s[1][1]), fmaxf(s[1][2], s[1][3]));
    float t2m = fmaxf(fmaxf(s[2][0], s[2][1]), fmaxf(s[2][2], s[2][3]));
    float t3m = fmaxf(fmaxf(s[3][0], s[3][1]), fmaxf(s[3][2], s[3][3]));
    float mt = fmaxf(fmaxf(t0m, t1m), fmaxf(t2m, t3m));
    mt = fmaxf(mt, __shfl_xor(mt, 16, 64));
    mt = fmaxf(mt, __shfl_xor(mt, 32, 64));

    // deferred rescale (T13); 8 nats = 11.5416 base-2 units
    const bool skip = __all(mt <= mrow + 11.5415603f);
    float mnew = mrow;
    if (!skip) {
      mnew = fmaxf(mrow, mt);
      const float alpha = exp2f(mrow - mnew);
      if (lane < 16) alphaArr[w * 16 + l15] = alpha;
      lsum *= alpha;
      mrow = mnew;
    }

    float psum = 0.f;
#pragma unroll
    for (int kt = 0; kt < 4; ++kt) {
      const float p0 = exp2f(s[kt][0] - mnew);
      const float p1 = exp2f(s[kt][1] - mnew);
      const float p2 = exp2f(s[kt][2] - mnew);
      const float p3 = exp2f(s[kt][3] - mnew);
      psum += (p0 + p1) + (p2 + p3);
      const int a0 = (kt * 32 + hi * 8) ^ sw;
      *(unsigned*)(prow + a0) = pk2(p0, p1);
      *(unsigned*)(prow + a0 + 4) = pk2(p2, p3);
    }
    lsum += psum;

    if (!skip) {
      const f32x4 av = *(const f32x4*)(alphaArr + w * 16 + 4 * hi);
#pragma unroll
      for (int ht = 0; ht < 4; ++ht) O[ht] *= av;
    }

    short8 pa0 = *(const short8*)(prow + ((hi * 16) ^ sw));
    short8 pa1 = *(const short8*)(prow + ((64 + hi * 16) ^ sw));
    const char* Vl = Lds + 65536 + (g * 4 + buf) * 8192;
    __builtin_amdgcn_s_setprio(1);
#pragma unroll
    for (int ht = 0; ht < 4; ++ht) {
      const char* vr = Vl + (ht * 16 + l15) * 128;
      short8 v0 = *(const short8*)(vr + ((hi * 16) ^ swr));
      short8 v1 = *(const short8*)(vr + ((64 + hi * 16) ^ swr));
      O[ht] = __builtin_amdgcn_mfma_f32_16x16x32_bf16(pa0, v0, O[ht], 0, 0, 0);
      O[ht] = __builtin_amdgcn_mfma_f32_16x16x32_bf16(pa1, v1, O[ht], 0, 0, 0);
    }
    __builtin_amdgcn_s_setprio(0);
  };

  // prologue: tiles 0,1 in flight; __syncthreads drains them (+ bias)
  stage_gl(0, 0);
  stage_gl(1, 1);
  __syncthreads();

#pragma unroll 1
  for (int ts = 0; ts < 16; ts += 2) {
    // issue next superstep's lds-destined loads; 2 tiles of compute cover
    if (ts + 2 < 16) {
      stage_gl(ts + 2, (ts + 2) & 3);
      stage_gl(ts + 3, (ts + 3) & 3);
    }
    tile_compute(ts, ts & 3);
    tile_compute(ts + 1, (ts + 1) & 3);
    __syncthreads();  // vmcnt drain: staged tiles landed before next reads
  }

  // per-query l (reduce over hi groups)
  lsum += __shfl_xor(lsum, 16, 64);
  lsum += __shfl_xor(lsum, 32, 64);

  // split-2 merge: group 1 publishes, group 0 combines + stores.
  float* mergeF = (float*)Lds;
  if (g == 1) {
    float* ml = mergeF + (qs * 64 + lane) * 18;
    ml[0] = mrow; ml[1] = lsum;
#pragma unroll
    for (int ht = 0; ht < 4; ++ht)
#pragma unroll
      for (int r = 0; r < 4; ++r) ml[2 + ht * 4 + r] = O[ht][r];
  }
  __syncthreads();
  if (g == 0) {
    const float* ml = mergeF + (qs * 64 + lane) * 18;
    const float mB = ml[0], lB = ml[1];
    const float mn = fmaxf(mrow, mB);
    const float aa = exp2f(mrow - mn);
    const float ab = exp2f(mB - mn);
    const float inv = 1.0f / (lsum * aa + lB * ab);
    float* ob = out + (long)(b * T_SEQ + q0 + qs * 16) * 64;
#pragma unroll
    for (int r = 0; r < 4; ++r) {
      const float aar = __shfl(aa, 4 * hi + r, 64);
      const float abr = __shfl(ab, 4 * hi + r, 64);
      const float invr = __shfl(inv, 4 * hi + r, 64);
#pragma unroll
      for (int ht = 0; ht < 4; ++ht)
        ob[(4 * hi + r) * 64 + ht * 16 + l15] =
            (O[ht][r] * aar + ml[2 + ht * 4 + r] * abr) * invr;
    }
  }
}

// ---------------- launch ----------------
extern "C" void kernel_launch(void* const* d_in, const int* in_sizes, int n_in,
                              void* d_out, int out_size, void* d_ws, size_t ws_size,
                              hipStream_t stream) {
  const float* X  = (const float*)d_in[0];
  const float* Wq = (const float*)d_in[1];
  const float* Wk = (const float*)d_in[2];
  const float* Wv = (const float*)d_in[3];
  const int* mask = (const int*)d_in[4];
  float* outp = (float*)d_out;

  const long NT = (long)NB * T_SEQ * HS;
  ushort_t* wsb = (ushort_t*)d_ws;
  ushort_t* Qb  = wsb;            // 2 MB
  ushort_t* Kb  = wsb + NT;       // 2 MB
  ushort_t* Vtb = wsb + 2 * NT;   // 2 MB (per-batch transposed V)
  ushort_t* Wb  = wsb + 3 * NT;   // 384 KB

  convw_kernel<<<48, 256, 0, stream>>>(Wq, Wk, Wv, Wb);
  proj_kernel<<<(NB * T_SEQ) / 64, 256, 0, stream>>>(X, Wb, Qb, Kb, Vtb);
  attn_kernel<<<256, 512, 0, stream>>>(Qb, Kb, Vtb, mask, outp);
}